// Round 4
// baseline (97.678 us; speedup 1.0000x reference)
//
#include <hip/hip_runtime.h>

// ScoreNet fused: central moments -> MLP -> analytic jacobian contraction.
// Round 8: attack the barrier-fenced critical path, not aggregate traffic
// (r7 showed per-block fixed work is not the cost: 2x amortization = +0.5us).
//  (a) W2a prefetched into 32 VGPRs at kernel top (sample-independent,
//      reused by both groups): h2 inner loop is pure FMA + LDS broadcast,
//      no L2-latency loads exposed after a barrier.
//  (b) Emb pipeline de-barriered: Fourier features in-register (1
//      transcendental per lane), partial via 16 uniform readlanes (SALU),
//      consumed only after a barrier shared with h1 staging.
//  (c) Both groups batched per phase -> 3 barriers/block total (was 6),
//      with ~1400 VALU instr of moments ahead of barrier #1 to absorb skew.
// r5/r7 evidence: kernel ~15us vs ~5-7us issue floor; stalls live between
// barriers (exposed load latency + skew), fills are a fixed ~81us.

static __device__ __forceinline__ float gelu_f(float x) {
    // Abramowitz-Stegun 7.1.26 erf (max err 1.5e-7), branch-free.
    float y = 0.7071067811865475f * x;
    float s = fabsf(y);
    float t = __builtin_amdgcn_rcpf(fmaf(0.3275911f, s, 1.0f));
    float p = t * fmaf(t, fmaf(t, fmaf(t, fmaf(t, 1.061405429f,
                    -1.453152027f), 1.421413741f), -0.284496736f), 0.254829592f);
    float e = __expf(-y * y);
    float ea = fmaf(-p, e, 1.0f);
    float erfv = copysignf(ea, y);
    return 0.5f * x * (1.0f + erfv);
}

// Wave64 sum via DPP: row_shr 1/2/4/8 accumulates lane 15 (mod 16) = row sum,
// row_bcast:15 folds rows 0->1, 2->3; row_bcast:31 folds halves; lane 63 has
// the total. bound_ctrl=true: invalid-source lanes read 0 (harmless for +).
#define DPP_ADD(v, ctrl) \
    v += __int_as_float(__builtin_amdgcn_update_dpp(0, __float_as_int(v), ctrl, 0xf, 0xf, true))

static __device__ __forceinline__ float wave_sum(float v) {
    DPP_ADD(v, 0x111);  // row_shr:1
    DPP_ADD(v, 0x112);  // row_shr:2
    DPP_ADD(v, 0x114);  // row_shr:4
    DPP_ADD(v, 0x118);  // row_shr:8
    DPP_ADD(v, 0x142);  // row_bcast:15
    DPP_ADD(v, 0x143);  // row_bcast:31
    return __int_as_float(__builtin_amdgcn_readlane(__float_as_int(v), 63));
}

#define TWO_PI_F 6.283185307179586f

__global__ __launch_bounds__(256, 4) void scorenet_fused(
    const float* __restrict__ x,      // [B,100,2]
    const float* __restrict__ t_in,   // [1]
    const float* __restrict__ Wf,     // [32]
    const float* __restrict__ embW,   // [64,64]
    const float* __restrict__ embB,   // [64]
    const float* __restrict__ W1,     // [12,64]
    const float* __restrict__ b1,     // [64]
    const float* __restrict__ W2a,    // [64,128]
    const float* __restrict__ b2a,    // [128]
    const float* __restrict__ W2b,    // [128,12]
    const float* __restrict__ b2b,    // [12]
    const float* __restrict__ W2c,    // [12,12]
    const float* __restrict__ b2c,    // [12]
    float* __restrict__ out,          // [B,100,2]
    int B)
{
    __shared__ float s_epart[4][64];        // emb matmul partials per wave
    __shared__ float s_a[2][64][4];         // h1 activations: [group][j][sample]
    __shared__ float s_part[2][4][2][4][64];// h2 partials: [g][sample][eo][wave][lane]
    __shared__ float s_w2bT[12][128];       // W2b transposed: [col][row]

    const int tid = threadIdx.x;
    const int lane = tid & 63;
    const int w = tid >> 6;
    const float tval = t_in[0];

    // Two sample-groups per block: group g sample = blockIdx*8 + 4g + w.
    const int sb0 = blockIdx.x * 8 + w;
    const int sb1 = sb0 + 4;
    const bool v0 = sb0 < B, v1 = sb1 < B;
    const int c0i = v0 ? sb0 : B - 1;
    const int c1i = v1 ? sb1 : B - 1;

    // Issue ALL point loads immediately (HBM latency hides under staging).
    const bool has2 = lane < 36;
    const float2* px0 = reinterpret_cast<const float2*>(x) + (size_t)c0i * 100;
    const float2* px1 = reinterpret_cast<const float2*>(x) + (size_t)c1i * 100;
    float2 pA[2], pB[2];
    pA[0] = px0[lane];  pB[0] = px0[has2 ? lane + 64 : lane];
    pA[1] = px1[lane];  pB[1] = px1[has2 ? lane + 64 : lane];

    // W2a prefetch: wave w owns rows j in [16w,16w+16); lane owns cols 2l,2l+1.
    // 32 VGPRs, sample-independent, reused by both groups' h2 loops.
    float2 wreg[16];
    {
        const float2* w2a2 = reinterpret_cast<const float2*>(W2a);
        #pragma unroll
        for (int jj = 0; jj < 16; ++jj)
            wreg[jj] = w2a2[((w << 4) + jj) * 64 + lane];
    }

    // Stage W2b (transposed) into LDS once per block; covered by barrier #1.
    #pragma unroll
    for (int i = tid; i < 1536; i += 256) {
        int row = i / 12, col = i - row * 12;
        s_w2bT[col][row] = W2b[i];
    }

    // Fourier features in-register: lane l holds f_l (sin for l<32, cos else).
    // No LDS, no barrier.
    float fxp = tval * Wf[lane & 31] * TWO_PI_F;
    float f = (lane < 32) ? sinf(fxp) : cosf(fxp);

    // Emb partial: wave w covers j in [16w,16w+16) via uniform readlanes
    // (SALU pipe, overlaps VALU). Consumed after barrier #1.
    {
        float ep = 0.0f;
        #pragma unroll
        for (int jj = 0; jj < 16; ++jj) {
            int j = (w << 4) + jj;
            float fj = __int_as_float(__builtin_amdgcn_readlane(__float_as_int(f), j));
            ep = fmaf(fj, embW[j * 64 + lane], ep);
        }
        s_epart[w][lane] = ep;
    }

    // ---- moments for BOTH groups (no barriers; absorbs wave skew) ----
    float ua[2], va[2], ub[2], vb[2];
    float m[2][12];   // wave-uniform after DPP reduction
    #pragma unroll
    for (int g = 0; g < 2; ++g) {
        float xa = pA[g].x, ya = pA[g].y;
        float xb = has2 ? pB[g].x : 0.0f;
        float yb = has2 ? pB[g].y : 0.0f;

        const float mux = wave_sum(xa + xb) * 0.01f;
        const float muy = wave_sum(ya + yb) * 0.01f;

        ua[g] = xa - mux;  va[g] = ya - muy;
        ub[g] = has2 ? (xb - mux) : 0.0f;   // zero => contributes 0 below
        vb[g] = has2 ? (yb - muy) : 0.0f;

        // order: (1,1)(2,0)(0,2)(2,1)(1,2)(3,0)(0,3)(2,2)(3,1)(1,3)(4,0)(0,4)
        float ms[12];
        {
            float uA = ua[g], vA = va[g], uB = ub[g], vB = vb[g];
            float u2 = uA * uA, v2 = vA * vA;
            ms[0] = uA * vA;   ms[1] = u2;        ms[2] = v2;
            ms[3] = u2 * vA;   ms[4] = uA * v2;
            ms[5] = u2 * uA;   ms[6] = v2 * vA;
            ms[7] = u2 * v2;   ms[8] = ms[5] * vA; ms[9] = uA * ms[6];
            ms[10] = u2 * u2;  ms[11] = v2 * v2;
            float w2 = uB * uB, z2 = vB * vB;
            ms[0] += uB * vB;  ms[1] += w2;       ms[2] += z2;
            ms[3] += w2 * vB;  ms[4] += uB * z2;
            ms[5] += w2 * uB;  ms[6] += z2 * vB;
            ms[7] += w2 * z2;  ms[8] += w2 * uB * vB; ms[9] += uB * z2 * vB;
            ms[10] += w2 * w2; ms[11] += z2 * z2;
        }
        #pragma unroll
        for (int k = 0; k < 12; ++k) m[g][k] = wave_sum(ms[k]);
    }

    __syncthreads();   // barrier #1: s_epart + s_w2bT ready

    const float embl = embB[lane]
        + ((s_epart[0][lane] + s_epart[1][lane])
         + (s_epart[2][lane] + s_epart[3][lane]));
    const float rst = rsqrtf(tval);

    // ---- h1 for both groups; lane owns unit `lane` (W1 column read once) ----
    {
        float a10 = b1[lane], a11 = b1[lane];
        #pragma unroll
        for (int k = 0; k < 12; ++k) {
            float wk = W1[k * 64 + lane];
            a10 = fmaf(m[0][k], wk, a10);
            a11 = fmaf(m[1][k], wk, a11);
        }
        s_a[0][lane][w] = gelu_f(a10) + embl;
        s_a[1][lane][w] = gelu_f(a11) + embl;
    }
    __syncthreads();   // barrier #2: s_a ready

    // ---- h2 partials for both groups: pure FMA + LDS broadcast (W2a in regs)
    #pragma unroll
    for (int g = 0; g < 2; ++g) {
        float4 plo = {0.f, 0.f, 0.f, 0.f};
        float4 phi = {0.f, 0.f, 0.f, 0.f};
        const float4* a4p = reinterpret_cast<const float4*>(&s_a[g][0][0]);
        #pragma unroll
        for (int jj = 0; jj < 16; ++jj) {
            float4 a4 = a4p[(w << 4) + jj];  // broadcast: a_j for 4 samples
            float2 ww = wreg[jj];
            plo.x = fmaf(a4.x, ww.x, plo.x);
            plo.y = fmaf(a4.y, ww.x, plo.y);
            plo.z = fmaf(a4.z, ww.x, plo.z);
            plo.w = fmaf(a4.w, ww.x, plo.w);
            phi.x = fmaf(a4.x, ww.y, phi.x);
            phi.y = fmaf(a4.y, ww.y, phi.y);
            phi.z = fmaf(a4.z, ww.y, phi.z);
            phi.w = fmaf(a4.w, ww.y, phi.w);
        }
        s_part[g][0][0][w][lane] = plo.x;
        s_part[g][1][0][w][lane] = plo.y;
        s_part[g][2][0][w][lane] = plo.z;
        s_part[g][3][0][w][lane] = plo.w;
        s_part[g][0][1][w][lane] = phi.x;
        s_part[g][1][1][w][lane] = phi.y;
        s_part[g][2][1][w][lane] = phi.z;
        s_part[g][3][1][w][lane] = phi.w;
    }
    __syncthreads();   // barrier #3: s_part ready (last barrier)

    const float2 bb2a = reinterpret_cast<const float2*>(b2a)[lane];

    #pragma unroll
    for (int g = 0; g < 2; ++g) {
        const bool valid = g ? v1 : v0;
        const int bc = g ? c1i : c0i;

        // Wave w reduces its own sample's partials. o = 2*lane, 2*lane+1.
        float acc0 = bb2a.x + ((s_part[g][w][0][0][lane] + s_part[g][w][0][1][lane])
                             + (s_part[g][w][0][2][lane] + s_part[g][w][0][3][lane]));
        float acc1 = bb2a.y + ((s_part[g][w][1][0][lane] + s_part[g][w][1][1][lane])
                             + (s_part[g][w][1][2][lane] + s_part[g][w][1][3][lane]));
        float h2lo = gelu_f(acc0), h2hi = gelu_f(acc1);

        // ---- h3 = gelu(h2 @ W2b + b2b): W2b from LDS (staged once/block).
        float h3[12];  // wave-uniform
        #pragma unroll
        for (int k = 0; k < 12; ++k) {
            float2 wk = *reinterpret_cast<const float2*>(&s_w2bT[k][2 * lane]);
            float p3 = fmaf(h2lo, wk.x, h2hi * wk.y);
            h3[k] = gelu_f(wave_sum(p3) + b2b[k]);
        }

        // ---- h = (h3 @ W2c + b2c) / sqrt(t): lane-parallel (lanes 0..11),
        // then readlane back to uniform.
        float hk = 0.0f;
        if (lane < 12) {
            hk = b2c[lane];
            #pragma unroll
            for (int j = 0; j < 12; ++j) hk = fmaf(h3[j], W2c[j * 12 + lane], hk);
            hk *= rst;
        }
        float h[12];
        #pragma unroll
        for (int k = 0; k < 12; ++k)
            h[k] = __int_as_float(__builtin_amdgcn_readlane(__float_as_int(hk), k));

        // ---- per-sample correction constants (mean-shift jacobian term).
        const float inv_n = 0.01f;
        float cc0 = (2.0f*h[3]*m[g][0] + h[4]*m[g][2] + 3.0f*h[5]*m[g][1] + 2.0f*h[7]*m[g][4]
                   + 3.0f*h[8]*m[g][3] + h[9]*m[g][6] + 4.0f*h[10]*m[g][5]) * inv_n;
        float cc1 = (h[3]*m[g][1] + 2.0f*h[4]*m[g][0] + 3.0f*h[6]*m[g][2] + 2.0f*h[7]*m[g][3]
                   + h[8]*m[g][5] + 3.0f*h[9]*m[g][4] + 4.0f*h[11]*m[g][6]) * inv_n;

        // cubic polynomial coefficients in (u, v) — all wave-uniform
        const float A1 = 2.0f*h[1], A2 = h[0],      A3 = 3.0f*h[5], A4 = 2.0f*h[3], A5 = h[4];
        const float A6 = 4.0f*h[10],A7 = 3.0f*h[8], A8 = 2.0f*h[7], A9 = h[9];
        const float B1 = h[0],      B2 = 2.0f*h[2], B3 = h[3],      B4 = 2.0f*h[4], B5 = 3.0f*h[6];
        const float B6 = h[8],      B7 = 2.0f*h[7], B8 = 3.0f*h[9], B9 = 4.0f*h[11];

        float2* pout = reinterpret_cast<float2*>(out) + (size_t)bc * 100;
        if (valid) {
            float u = ua[g], v = va[g];
            float u2 = u*u, v2 = v*v;
            float o0 = A1*u + A2*v + A3*u2 + A4*u*v + A5*v2 + A6*u2*u + A7*u2*v + A8*u*v2 + A9*v2*v - cc0;
            float o1 = B1*u + B2*v + B3*u2 + B4*u*v + B5*v2 + B6*u2*u + B7*u2*v + B8*u*v2 + B9*v2*v - cc1;
            float2 r; r.x = o0; r.y = o1;
            pout[lane] = r;
            if (has2) {
                float uu = ub[g], vv = vb[g];
                float uu2 = uu*uu, vv2 = vv*vv;
                float q0 = A1*uu + A2*vv + A3*uu2 + A4*uu*vv + A5*vv2 + A6*uu2*uu + A7*uu2*vv + A8*uu*vv2 + A9*vv2*vv - cc0;
                float q1 = B1*uu + B2*vv + B3*uu2 + B4*uu*vv + B5*vv2 + B6*uu2*uu + B7*uu2*vv + B8*uu*vv2 + B9*vv2*vv - cc1;
                float2 r2; r2.x = q0; r2.y = q1;
                pout[lane + 64] = r2;
            }
        }
    }
}

extern "C" void kernel_launch(void* const* d_in, const int* in_sizes, int n_in,
                              void* d_out, int out_size, void* d_ws, size_t ws_size,
                              hipStream_t stream) {
    const float* x    = (const float*)d_in[0];
    const float* t    = (const float*)d_in[1];
    // d_in[2] = K (exponent table) — baked into the kernel as compile-time constants.
    const float* Wf   = (const float*)d_in[3];
    const float* embW = (const float*)d_in[4];
    const float* embB = (const float*)d_in[5];
    const float* W1   = (const float*)d_in[6];
    const float* b1   = (const float*)d_in[7];
    const float* W2a  = (const float*)d_in[8];
    const float* b2a  = (const float*)d_in[9];
    const float* W2b  = (const float*)d_in[10];
    const float* b2b  = (const float*)d_in[11];
    const float* W2c  = (const float*)d_in[12];
    const float* b2c  = (const float*)d_in[13];

    const int B = in_sizes[0] / 200;            // [B,100,2]
    const int blocks = (B + 7) / 8;             // 8 samples (2 groups of 4 waves)

    scorenet_fused<<<blocks, 256, 0, stream>>>(
        x, t, Wf, embW, embB, W1, b1, W2a, b2a, W2b, b2b, W2c, b2c,
        (float*)d_out, B);
}

// Round 6
// 95.992 us; speedup vs baseline: 1.0176x; 1.0176x over previous
//
#include <hip/hip_runtime.h>

// ScoreNet fused: central moments -> MLP -> analytic jacobian contraction.
// Round 9 RESUBMIT (r9 bench died to container infra failure, no signal).
// Theory unchanged: occupancy, not schedule. r5/r7/r8 varied barriers (6->3),
// per-block work (2x), and W2a placement (L1 vs VGPR) -- kernel portion pinned
// at ~15-16us every time => those were not the bottleneck. Common factor: only
// 4 waves/SIMD resident (VGPR>64), VALUBusy ~25-30% => latency-bound on
// dependent DPP chains / transcendentals / head-of-block HBM latency.
// This round: lean 4-sample/block structure, grid 2048 (8 blocks/CU, LDS
// 16KB), __launch_bounds__(256,8) to pin VGPR<=64 -> 32 waves/CU (2x TLP).
// Dropped: W2a VGPR prefetch (32 regs), 2-group batching (state doubling).
// Kept: W2b LDS staging, in-register Fourier + readlane emb (no extra
// barriers; 3 barriers total), wave-uniform values in SGPRs via wave_sum.

static __device__ __forceinline__ float gelu_f(float x) {
    // Abramowitz-Stegun 7.1.26 erf (max err 1.5e-7), branch-free.
    float y = 0.7071067811865475f * x;
    float s = fabsf(y);
    float t = __builtin_amdgcn_rcpf(fmaf(0.3275911f, s, 1.0f));
    float p = t * fmaf(t, fmaf(t, fmaf(t, fmaf(t, 1.061405429f,
                    -1.453152027f), 1.421413741f), -0.284496736f), 0.254829592f);
    float e = __expf(-y * y);
    float ea = fmaf(-p, e, 1.0f);
    float erfv = copysignf(ea, y);
    return 0.5f * x * (1.0f + erfv);
}

// Wave64 sum via DPP: row_shr 1/2/4/8 accumulates lane 15 (mod 16) = row sum,
// row_bcast:15 folds rows 0->1, 2->3; row_bcast:31 folds halves; lane 63 has
// the total. bound_ctrl=true: invalid-source lanes read 0 (harmless for +).
// Returns via readlane => SGPR-resident (keeps VGPR pressure low).
#define DPP_ADD(v, ctrl) \
    v += __int_as_float(__builtin_amdgcn_update_dpp(0, __float_as_int(v), ctrl, 0xf, 0xf, true))

static __device__ __forceinline__ float wave_sum(float v) {
    DPP_ADD(v, 0x111);  // row_shr:1
    DPP_ADD(v, 0x112);  // row_shr:2
    DPP_ADD(v, 0x114);  // row_shr:4
    DPP_ADD(v, 0x118);  // row_shr:8
    DPP_ADD(v, 0x142);  // row_bcast:15
    DPP_ADD(v, 0x143);  // row_bcast:31
    return __int_as_float(__builtin_amdgcn_readlane(__float_as_int(v), 63));
}

#define TWO_PI_F 6.283185307179586f

__global__ __launch_bounds__(256, 8) void scorenet_fused(
    const float* __restrict__ x,      // [B,100,2]
    const float* __restrict__ t_in,   // [1]
    const float* __restrict__ Wf,     // [32]
    const float* __restrict__ embW,   // [64,64]
    const float* __restrict__ embB,   // [64]
    const float* __restrict__ W1,     // [12,64]
    const float* __restrict__ b1,     // [64]
    const float* __restrict__ W2a,    // [64,128]
    const float* __restrict__ b2a,    // [128]
    const float* __restrict__ W2b,    // [128,12]
    const float* __restrict__ b2b,    // [12]
    const float* __restrict__ W2c,    // [12,12]
    const float* __restrict__ b2c,    // [12]
    float* __restrict__ out,          // [B,100,2]
    int B)
{
    __shared__ float s_epart[4][64];       // emb matmul partials per wave
    __shared__ float s_a[64][4];           // h1 activations transposed: [j][sample]
    __shared__ float s_part[4][2][4][64];  // h2 partials: [sample][eo][wave][lane]
    __shared__ float s_w2bT[12][128];      // W2b transposed: [col][row]

    const int tid = threadIdx.x;
    const int lane = tid & 63;
    const int w = tid >> 6;
    const float tval = t_in[0];

    const int b = blockIdx.x * 4 + w;
    const bool valid = b < B;
    const int bc = valid ? b : B - 1;     // clamp: no early return (barriers below)

    // Issue this sample's point loads immediately (HBM latency hides under
    // the staging + embedding + moments phase).
    const float2* px = reinterpret_cast<const float2*>(x) + (size_t)bc * 100;
    const bool has2 = lane < 36;
    float2 p0 = px[lane];
    float2 p1 = px[has2 ? lane + 64 : lane];

    // Stage W2b (transposed) into LDS once per block; covered by barrier #1.
    #pragma unroll
    for (int i = tid; i < 1536; i += 256) {
        int row = i / 12, col = i - row * 12;
        s_w2bT[col][row] = W2b[i];
    }

    // Fourier features in-register: lane l holds f_l (sin for l<32, cos else).
    float fxp = tval * Wf[lane & 31] * TWO_PI_F;
    float f = (lane < 32) ? sinf(fxp) : cosf(fxp);

    // Emb partial: wave w covers j in [16w,16w+16) via uniform readlanes.
    {
        float ep = 0.0f;
        #pragma unroll
        for (int jj = 0; jj < 16; ++jj) {
            int j = (w << 4) + jj;
            float fj = __int_as_float(__builtin_amdgcn_readlane(__float_as_int(f), j));
            ep = fmaf(fj, embW[j * 64 + lane], ep);
        }
        s_epart[w][lane] = ep;
    }

    // ---- moments (no barriers; ~700 VALU instr absorbs wave skew) ----
    float xa = p0.x, ya = p0.y;
    float xb = has2 ? p1.x : 0.0f;
    float yb = has2 ? p1.y : 0.0f;

    const float mux = wave_sum(xa + xb) * 0.01f;
    const float muy = wave_sum(ya + yb) * 0.01f;

    float ua = xa - mux, va = ya - muy;
    float ub = has2 ? (xb - mux) : 0.0f;   // zero => contributes 0 below
    float vb = has2 ? (yb - muy) : 0.0f;

    // order: (1,1)(2,0)(0,2)(2,1)(1,2)(3,0)(0,3)(2,2)(3,1)(1,3)(4,0)(0,4)
    float ms[12];
    {
        float u2 = ua * ua, v2 = va * va;
        ms[0] = ua * va;   ms[1] = u2;        ms[2] = v2;
        ms[3] = u2 * va;   ms[4] = ua * v2;
        ms[5] = u2 * ua;   ms[6] = v2 * va;
        ms[7] = u2 * v2;   ms[8] = ms[5] * va; ms[9] = ua * ms[6];
        ms[10] = u2 * u2;  ms[11] = v2 * v2;
        float w2 = ub * ub, z2 = vb * vb;
        ms[0] += ub * vb;  ms[1] += w2;       ms[2] += z2;
        ms[3] += w2 * vb;  ms[4] += ub * z2;
        ms[5] += w2 * ub;  ms[6] += z2 * vb;
        ms[7] += w2 * z2;  ms[8] += w2 * ub * vb; ms[9] += ub * z2 * vb;
        ms[10] += w2 * w2; ms[11] += z2 * z2;
    }
    float m[12];   // wave-uniform (SGPR after readlane)
    #pragma unroll
    for (int k = 0; k < 12; ++k) m[k] = wave_sum(ms[k]);

    __syncthreads();   // barrier #1: s_epart + s_w2bT ready

    const float embl = embB[lane]
        + ((s_epart[0][lane] + s_epart[1][lane])
         + (s_epart[2][lane] + s_epart[3][lane]));
    const float rst = rsqrtf(tval);

    // ---- h1 = gelu(m @ W1 + b1) + emb; lane owns unit `lane`
    float a1 = b1[lane];
    #pragma unroll
    for (int k = 0; k < 12; ++k) a1 = fmaf(m[k], W1[k * 64 + lane], a1);
    s_a[lane][w] = gelu_f(a1) + embl;
    __syncthreads();   // barrier #2: s_a ready

    // ---- h2 = gelu((h1+emb) @ W2a + b2a), block-cooperative.
    // Wave w handles j in [16w,16w+16) for ALL 4 samples: W2a read once per
    // block; with 8 blocks/CU reading identical addresses, L1 serves most.
    float4 plo = {0.f, 0.f, 0.f, 0.f};
    float4 phi = {0.f, 0.f, 0.f, 0.f};
    {
        const float4* a4p = reinterpret_cast<const float4*>(&s_a[0][0]);
        const float2* w2a2 = reinterpret_cast<const float2*>(W2a);
        #pragma unroll
        for (int jj = 0; jj < 16; ++jj) {
            const int j = (w << 4) + jj;
            float4 a4 = a4p[j];              // broadcast: a_j for 4 samples
            float2 ww = w2a2[j * 64 + lane]; // W2a[j][2l], W2a[j][2l+1]
            plo.x = fmaf(a4.x, ww.x, plo.x);
            plo.y = fmaf(a4.y, ww.x, plo.y);
            plo.z = fmaf(a4.z, ww.x, plo.z);
            plo.w = fmaf(a4.w, ww.x, plo.w);
            phi.x = fmaf(a4.x, ww.y, phi.x);
            phi.y = fmaf(a4.y, ww.y, phi.y);
            phi.z = fmaf(a4.z, ww.y, phi.z);
            phi.w = fmaf(a4.w, ww.y, phi.w);
        }
    }
    s_part[0][0][w][lane] = plo.x;
    s_part[1][0][w][lane] = plo.y;
    s_part[2][0][w][lane] = plo.z;
    s_part[3][0][w][lane] = plo.w;
    s_part[0][1][w][lane] = phi.x;
    s_part[1][1][w][lane] = phi.y;
    s_part[2][1][w][lane] = phi.z;
    s_part[3][1][w][lane] = phi.w;
    __syncthreads();   // barrier #3: s_part ready (last barrier)

    // Wave w reduces its own sample's partials. o = 2*lane, 2*lane+1.
    const float2 bb2a = reinterpret_cast<const float2*>(b2a)[lane];
    float acc0 = bb2a.x + ((s_part[w][0][0][lane] + s_part[w][0][1][lane])
                         + (s_part[w][0][2][lane] + s_part[w][0][3][lane]));
    float acc1 = bb2a.y + ((s_part[w][1][0][lane] + s_part[w][1][1][lane])
                         + (s_part[w][1][2][lane] + s_part[w][1][3][lane]));
    float h2lo = gelu_f(acc0), h2hi = gelu_f(acc1);

    // ---- h3 = gelu(h2 @ W2b + b2b): W2b from LDS (staged once/block).
    float h3[12];  // wave-uniform (SGPR after readlane)
    #pragma unroll
    for (int k = 0; k < 12; ++k) {
        float2 wk = *reinterpret_cast<const float2*>(&s_w2bT[k][2 * lane]);
        float p3 = fmaf(h2lo, wk.x, h2hi * wk.y);
        h3[k] = gelu_f(wave_sum(p3) + b2b[k]);
    }

    // ---- h = (h3 @ W2c + b2c) / sqrt(t): lane-parallel (lanes 0..11),
    // then readlane back to uniform (SGPR).
    float hk = 0.0f;
    if (lane < 12) {
        hk = b2c[lane];
        #pragma unroll
        for (int j = 0; j < 12; ++j) hk = fmaf(h3[j], W2c[j * 12 + lane], hk);
        hk *= rst;
    }
    float h[12];
    #pragma unroll
    for (int k = 0; k < 12; ++k)
        h[k] = __int_as_float(__builtin_amdgcn_readlane(__float_as_int(hk), k));

    // ---- per-sample correction constants (mean-shift jacobian term).
    const float inv_n = 0.01f;
    float c0 = (2.0f*h[3]*m[0] + h[4]*m[2] + 3.0f*h[5]*m[1] + 2.0f*h[7]*m[4]
              + 3.0f*h[8]*m[3] + h[9]*m[6] + 4.0f*h[10]*m[5]) * inv_n;
    float c1 = (h[3]*m[1] + 2.0f*h[4]*m[0] + 3.0f*h[6]*m[2] + 2.0f*h[7]*m[3]
              + h[8]*m[5] + 3.0f*h[9]*m[4] + 4.0f*h[11]*m[6]) * inv_n;

    // cubic polynomial coefficients in (u, v) — all wave-uniform
    const float A1 = 2.0f*h[1], A2 = h[0],      A3 = 3.0f*h[5], A4 = 2.0f*h[3], A5 = h[4];
    const float A6 = 4.0f*h[10],A7 = 3.0f*h[8], A8 = 2.0f*h[7], A9 = h[9];
    const float B1 = h[0],      B2 = 2.0f*h[2], B3 = h[3],      B4 = 2.0f*h[4], B5 = 3.0f*h[6];
    const float B6 = h[8],      B7 = 2.0f*h[7], B8 = 3.0f*h[9], B9 = 4.0f*h[11];

    float2* pout = reinterpret_cast<float2*>(out) + (size_t)bc * 100;
    if (valid) {
        float u = ua, v = va;
        float u2 = u*u, v2 = v*v;
        float o0 = A1*u + A2*v + A3*u2 + A4*u*v + A5*v2 + A6*u2*u + A7*u2*v + A8*u*v2 + A9*v2*v - c0;
        float o1 = B1*u + B2*v + B3*u2 + B4*u*v + B5*v2 + B6*u2*u + B7*u2*v + B8*u*v2 + B9*v2*v - c1;
        float2 r; r.x = o0; r.y = o1;
        pout[lane] = r;
        if (has2) {
            float uu = ub, vv = vb;
            float uu2 = uu*uu, vv2 = vv*vv;
            float q0 = A1*uu + A2*vv + A3*uu2 + A4*uu*vv + A5*vv2 + A6*uu2*uu + A7*uu2*vv + A8*uu*vv2 + A9*vv2*vv - c0;
            float q1 = B1*uu + B2*vv + B3*uu2 + B4*uu*vv + B5*vv2 + B6*uu2*uu + B7*uu2*vv + B8*uu*vv2 + B9*vv2*vv - c1;
            float2 r2; r2.x = q0; r2.y = q1;
            pout[lane + 64] = r2;
        }
    }
}

extern "C" void kernel_launch(void* const* d_in, const int* in_sizes, int n_in,
                              void* d_out, int out_size, void* d_ws, size_t ws_size,
                              hipStream_t stream) {
    const float* x    = (const float*)d_in[0];
    const float* t    = (const float*)d_in[1];
    // d_in[2] = K (exponent table) — baked into the kernel as compile-time constants.
    const float* Wf   = (const float*)d_in[3];
    const float* embW = (const float*)d_in[4];
    const float* embB = (const float*)d_in[5];
    const float* W1   = (const float*)d_in[6];
    const float* b1   = (const float*)d_in[7];
    const float* W2a  = (const float*)d_in[8];
    const float* b2a  = (const float*)d_in[9];
    const float* W2b  = (const float*)d_in[10];
    const float* b2b  = (const float*)d_in[11];
    const float* W2c  = (const float*)d_in[12];
    const float* b2c  = (const float*)d_in[13];

    const int B = in_sizes[0] / 200;            // [B,100,2]
    const int blocks = (B + 3) / 4;             // 4 samples (waves) per block

    scorenet_fused<<<blocks, 256, 0, stream>>>(
        x, t, Wf, embW, embB, W1, b1, W2a, b2a, W2b, b2b, W2c, b2c,
        (float*)d_out, B);
}